// Round 1
// baseline (1188.530 us; speedup 1.0000x reference)
//
#include <hip/hip_runtime.h>
#include <stdint.h>

#define NB 2       // batch
#define SL 4096    // seq len
#define NH 16      // heads
#define HD 128     // head dim
#define DS 256     // d_state
#define CK 256     // chunk
#define NCH 16     // chunks per seq
#define NSQ 4      // 2*NB sequences (fwd+bwd)
#define DI 2048    // NH*HD

__device__ __forceinline__ int tor(int dir, int t) { return dir ? (SL - 1 - t) : t; }

__device__ __forceinline__ unsigned short f2bf(float f) {
  unsigned int u = __float_as_uint(f);
  u = u + 0x7fffu + ((u >> 16) & 1u);   // RNE
  return (unsigned short)(u >> 16);
}
__device__ __forceinline__ float bf2f(unsigned short s) {
  return __uint_as_float(((unsigned int)s) << 16);
}

// ---- prep: softplus(dt), per-chunk cumsum of dA, chunk decay -----------------
// cs/dtv layout: [s][j][h][i], i in [0,CK)
__global__ __launch_bounds__(256) void kprep(const float* __restrict__ dt,
                                             const float* __restrict__ A_log,
                                             float* __restrict__ cs,
                                             float* __restrict__ dtv,
                                             float* __restrict__ cdec) {
  int sj = blockIdx.x;               // s*NCH + j
  int s = sj >> 4, j = sj & 15;
  int b = s & 1, dir = s >> 1;
  int i = threadIdx.x;
  int to = tor(dir, j * CK + i);
  __shared__ float sbuf[CK];
  for (int h = 0; h < NH; ++h) {
    float a = -expf(A_log[h]);
    float raw = dt[((size_t)(b * SL + to)) * (2 * NH) + dir * NH + h];
    float sp = (raw > 20.f) ? raw : log1pf(expf(raw));
    float da = sp * a;
    __syncthreads();
    sbuf[i] = da;
    __syncthreads();
    for (int off = 1; off < CK; off <<= 1) {
      float v = (i >= off) ? sbuf[i - off] : 0.f;
      __syncthreads();
      sbuf[i] += v;
      __syncthreads();
    }
    float csv = sbuf[i];
    size_t base = ((size_t)sj * NH + h) * CK;
    cs[base + i] = csv;
    dtv[base + i] = sp;
    if (i == CK - 1) cdec[sj * NH + h] = expf(csv);
  }
}

// ---- CB[i,k] = sum_n C[i,n]*B[k,n], lower-triangle tiles only ----------------
__global__ __launch_bounds__(256) void kcb(const float* __restrict__ BC,
                                           float* __restrict__ CBbuf) {
  int blk = blockIdx.x;
  int tile = blk & 15, sj = blk >> 4;
  int it = tile >> 2, kt = tile & 3;
  if (kt > it) return;                       // masked region never read
  int s = sj >> 4, j = sj & 15;
  int b = s & 1, dir = s >> 1;
  int it0 = it * 64, kt0 = kt * 64;
  __shared__ float Ct[32][64];               // [n][i]
  __shared__ float Bt[32][64];               // [n][k]
  int tid = threadIdx.x;
  int ti = tid >> 4, tk = tid & 15;
  int row = tid >> 2;
  int nb = (tid & 3) * 8;
  float acc[4][4] = {};
  for (int n0 = 0; n0 < DS; n0 += 32) {
    const float* csrc = BC + ((size_t)(b * SL + tor(dir, j * CK + it0 + row))) * (2 * DS) + DS + n0 + nb;
    float4 c0 = ((const float4*)csrc)[0];
    float4 c1 = ((const float4*)csrc)[1];
    const float* bsrc = BC + ((size_t)(b * SL + tor(dir, j * CK + kt0 + row))) * (2 * DS) + n0 + nb;
    float4 b0 = ((const float4*)bsrc)[0];
    float4 b1 = ((const float4*)bsrc)[1];
    __syncthreads();
    Ct[nb + 0][row] = c0.x; Ct[nb + 1][row] = c0.y; Ct[nb + 2][row] = c0.z; Ct[nb + 3][row] = c0.w;
    Ct[nb + 4][row] = c1.x; Ct[nb + 5][row] = c1.y; Ct[nb + 6][row] = c1.z; Ct[nb + 7][row] = c1.w;
    Bt[nb + 0][row] = b0.x; Bt[nb + 1][row] = b0.y; Bt[nb + 2][row] = b0.z; Bt[nb + 3][row] = b0.w;
    Bt[nb + 4][row] = b1.x; Bt[nb + 5][row] = b1.y; Bt[nb + 6][row] = b1.z; Bt[nb + 7][row] = b1.w;
    __syncthreads();
#pragma unroll
    for (int nn = 0; nn < 32; ++nn) {
      float4 cv = *(const float4*)&Ct[nn][ti * 4];
      float4 bv = *(const float4*)&Bt[nn][tk * 4];
      float cr[4] = {cv.x, cv.y, cv.z, cv.w};
      float br[4] = {bv.x, bv.y, bv.z, bv.w};
#pragma unroll
      for (int a = 0; a < 4; ++a)
#pragma unroll
        for (int c = 0; c < 4; ++c) acc[a][c] += cr[a] * br[c];
    }
  }
#pragma unroll
  for (int a = 0; a < 4; ++a) {
    int i = it0 + ti * 4 + a;
    *(float4*)&CBbuf[((size_t)sj * CK + i) * CK + kt0 + tk * 4] =
        make_float4(acc[a][0], acc[a][1], acc[a][2], acc[a][3]);
  }
}

// ---- per-chunk states: S[n,p] = sum_k w[k]*B[k,n]*x[k,p], w = decay_states*dt
// stored bf16 into prevbuf [s][j][h][n][p] (later scanned in place)
__global__ __launch_bounds__(256) void kstates(const float* __restrict__ xg,
                                               const float* __restrict__ BC,
                                               const float* __restrict__ cs,
                                               const float* __restrict__ dtv,
                                               unsigned short* __restrict__ prevbuf) {
  int blk = blockIdx.x;
  int ntile = blk & 1;
  int inst = blk >> 1;                 // (s*NCH+j)*NH + h
  int h = inst & 15, sj = inst >> 4;
  int s = sj >> 4, j = sj & 15;
  int b = s & 1, dir = s >> 1;
  int nt0 = ntile * 128;
  __shared__ float wAll[CK];
  __shared__ float Bw[32][128];
  __shared__ float Xs[32][128];
  int tid = threadIdx.x;
  {
    size_t base = ((size_t)sj * NH + h) * CK;
    float cl = cs[base + CK - 1];
    wAll[tid] = expf(cl - cs[base + tid]) * dtv[base + tid];
  }
  float acc[8][8] = {};
  int tn = tid >> 4, tp = tid & 15;
  int skk = tid >> 3;
  int soff = (tid & 7) * 16;
  for (int k0 = 0; k0 < CK; k0 += 32) {
    int to = tor(dir, j * CK + k0 + skk);
    const float* bsrc = BC + ((size_t)(b * SL + to)) * (2 * DS) + nt0 + soff;
    float4 bb[4];
    bb[0] = ((const float4*)bsrc)[0]; bb[1] = ((const float4*)bsrc)[1];
    bb[2] = ((const float4*)bsrc)[2]; bb[3] = ((const float4*)bsrc)[3];
    const float* xsrc = xg + ((size_t)(b * SL + to)) * DI + h * HD + soff;
    float4 xx[4];
    xx[0] = ((const float4*)xsrc)[0]; xx[1] = ((const float4*)xsrc)[1];
    xx[2] = ((const float4*)xsrc)[2]; xx[3] = ((const float4*)xsrc)[3];
    __syncthreads();
    float w = wAll[k0 + skk];
#pragma unroll
    for (int q = 0; q < 4; ++q) {
      bb[q].x *= w; bb[q].y *= w; bb[q].z *= w; bb[q].w *= w;
      *(float4*)&Bw[skk][soff + q * 4] = bb[q];
      *(float4*)&Xs[skk][soff + q * 4] = xx[q];
    }
    __syncthreads();
#pragma unroll
    for (int q = 0; q < 32; ++q) {
      float4 a0 = *(const float4*)&Bw[q][tn * 8];
      float4 a1 = *(const float4*)&Bw[q][tn * 8 + 4];
      float4 c0 = *(const float4*)&Xs[q][tp * 8];
      float4 c1 = *(const float4*)&Xs[q][tp * 8 + 4];
      float ar[8] = {a0.x, a0.y, a0.z, a0.w, a1.x, a1.y, a1.z, a1.w};
      float cr[8] = {c0.x, c0.y, c0.z, c0.w, c1.x, c1.y, c1.z, c1.w};
#pragma unroll
      for (int r = 0; r < 8; ++r)
#pragma unroll
        for (int c = 0; c < 8; ++c) acc[r][c] += ar[r] * cr[c];
    }
  }
#pragma unroll
  for (int r = 0; r < 8; ++r) {
    int n = nt0 + tn * 8 + r;
    uint4 pk;
    pk.x = (unsigned int)f2bf(acc[r][0]) | ((unsigned int)f2bf(acc[r][1]) << 16);
    pk.y = (unsigned int)f2bf(acc[r][2]) | ((unsigned int)f2bf(acc[r][3]) << 16);
    pk.z = (unsigned int)f2bf(acc[r][4]) | ((unsigned int)f2bf(acc[r][5]) << 16);
    pk.w = (unsigned int)f2bf(acc[r][6]) | ((unsigned int)f2bf(acc[r][7]) << 16);
    *(uint4*)(prevbuf + ((size_t)inst * DS + n) * HD + tp * 8) = pk;
  }
}

// ---- inter-chunk recurrence (in place): prev[j] = carry; carry = carry*cdec + S[j]
__global__ __launch_bounds__(256) void kscan(unsigned short* __restrict__ prevbuf,
                                             const float* __restrict__ cdec) {
  int g = blockIdx.x * 256 + threadIdx.x;
  int pp = g & 127;
  int n = (g >> 7) & 255;
  int h = (g >> 15) & 15;
  int s = g >> 19;
  size_t base = (((size_t)(s * NCH) * NH + h) * DS + n) * HD + pp;
  const size_t stride = (size_t)NH * DS * HD;
  float carry = 0.f;
  for (int j = 0; j < NCH; ++j) {
    size_t idx = base + (size_t)j * stride;
    float sv = bf2f(prevbuf[idx]);
    prevbuf[idx] = f2bf(carry);
    carry = carry * cdec[(s * NCH + j) * NH + h] + sv;
  }
}

// ---- y[i,p] = sum_{k<=i} CB[i,k] e^{cs_i-cs_k} dt_k x[k,p] + e^{cs_i} sum_n C[i,n] prev[n,p]
// single K=512 GEMM: [G | C*e^{cs_i}] @ [x ; prev]
__global__ __launch_bounds__(256) void ky(const float* __restrict__ xg,
                                          const float* __restrict__ BC,
                                          const float* __restrict__ cs,
                                          const float* __restrict__ dtv,
                                          const float* __restrict__ CBbuf,
                                          const unsigned short* __restrict__ prevbuf,
                                          float* __restrict__ ytmp) {
  int blk = blockIdx.x;
  int itile = blk & 1;
  int inst = blk >> 1;
  int h = inst & 15, sj = inst >> 4;
  int s = sj >> 4, j = sj & 15;
  int b = s & 1, dir = s >> 1;
  int it0 = itile * 128;
  __shared__ float Lt[32][128];   // [k][i]
  __shared__ float Rt[32][128];   // [k][p]
  __shared__ float csA[CK];
  __shared__ float dtA[CK];
  __shared__ float eI[128];
  int tid = threadIdx.x;
  {
    size_t base = ((size_t)sj * NH + h) * CK;
    csA[tid] = cs[base + tid];
    dtA[tid] = dtv[base + tid];
    if (tid < 128) eI[tid] = expf(cs[base + it0 + tid]);
  }
  float acc[8][8] = {};
  int tii = tid >> 4, tp = tid & 15;
  int lii = tid & 127;
  int lk0 = (tid >> 7) * 16;
  int rkk = tid >> 3;
  int rpp = (tid & 7) * 16;
  for (int k0 = 0; k0 < 2 * CK; k0 += 32) {
    float lv[16], rv[16];
    if (k0 < CK) {
      const float* lsrc = CBbuf + ((size_t)sj * CK + it0 + lii) * CK + k0 + lk0;
#pragma unroll
      for (int q = 0; q < 4; ++q) {
        float4 v = ((const float4*)lsrc)[q];
        lv[q * 4 + 0] = v.x; lv[q * 4 + 1] = v.y; lv[q * 4 + 2] = v.z; lv[q * 4 + 3] = v.w;
      }
      int to = tor(dir, j * CK + k0 + rkk);
      const float* rsrc = xg + ((size_t)(b * SL + to)) * DI + h * HD + rpp;
#pragma unroll
      for (int q = 0; q < 4; ++q) {
        float4 v = ((const float4*)rsrc)[q];
        rv[q * 4 + 0] = v.x; rv[q * 4 + 1] = v.y; rv[q * 4 + 2] = v.z; rv[q * 4 + 3] = v.w;
      }
    } else {
      int to = tor(dir, j * CK + it0 + lii);
      const float* lsrc = BC + ((size_t)(b * SL + to)) * (2 * DS) + DS + (k0 - CK) + lk0;
#pragma unroll
      for (int q = 0; q < 4; ++q) {
        float4 v = ((const float4*)lsrc)[q];
        lv[q * 4 + 0] = v.x; lv[q * 4 + 1] = v.y; lv[q * 4 + 2] = v.z; lv[q * 4 + 3] = v.w;
      }
      const uint4* psrc = (const uint4*)(prevbuf + ((size_t)inst * DS + (k0 - CK) + rkk) * HD + rpp);
      uint4 u0 = psrc[0], u1 = psrc[1];
      unsigned int uu[8] = {u0.x, u0.y, u0.z, u0.w, u1.x, u1.y, u1.z, u1.w};
#pragma unroll
      for (int q = 0; q < 8; ++q) {
        rv[q * 2 + 0] = __uint_as_float(uu[q] << 16);
        rv[q * 2 + 1] = __uint_as_float(uu[q] & 0xffff0000u);
      }
    }
    __syncthreads();
    if (k0 < CK) {
      int ii = it0 + lii;
      float ci = csA[ii];
#pragma unroll
      for (int q = 0; q < 16; ++q) {
        int k = k0 + lk0 + q;
        Lt[lk0 + q][lii] = (k <= ii) ? lv[q] * expf(ci - csA[k]) * dtA[k] : 0.f;
      }
    } else {
      float e = eI[lii];
#pragma unroll
      for (int q = 0; q < 16; ++q) Lt[lk0 + q][lii] = lv[q] * e;
    }
#pragma unroll
    for (int q = 0; q < 4; ++q)
      *(float4*)&Rt[rkk][rpp + q * 4] =
          make_float4(rv[q * 4], rv[q * 4 + 1], rv[q * 4 + 2], rv[q * 4 + 3]);
    __syncthreads();
#pragma unroll
    for (int q = 0; q < 32; ++q) {
      float4 a0 = *(const float4*)&Lt[q][tii * 8];
      float4 a1 = *(const float4*)&Lt[q][tii * 8 + 4];
      float4 c0 = *(const float4*)&Rt[q][tp * 8];
      float4 c1 = *(const float4*)&Rt[q][tp * 8 + 4];
      float ar[8] = {a0.x, a0.y, a0.z, a0.w, a1.x, a1.y, a1.z, a1.w};
      float cr[8] = {c0.x, c0.y, c0.z, c0.w, c1.x, c1.y, c1.z, c1.w};
#pragma unroll
      for (int r = 0; r < 8; ++r)
#pragma unroll
        for (int c = 0; c < 8; ++c) acc[r][c] += ar[r] * cr[c];
    }
  }
#pragma unroll
  for (int r = 0; r < 8; ++r) {
    int i = it0 + tii * 8 + r;
    float* dst = ytmp + ((size_t)s * SL + j * CK + i) * DI + h * HD + tp * 8;
    *(float4*)dst = make_float4(acc[r][0], acc[r][1], acc[r][2], acc[r][3]);
    *(float4*)(dst + 4) = make_float4(acc[r][4], acc[r][5], acc[r][6], acc[r][7]);
  }
}

// ---- final: out = roll(y_fw) + flip(roll(y_bw)) + x * repeat(x@W^T + D) -------
__global__ __launch_bounds__(256) void kfinal(const float* __restrict__ xg,
                                              const float* __restrict__ Wg,
                                              const float* __restrict__ Dg,
                                              const float* __restrict__ ytmp,
                                              float* __restrict__ out) {
  int bid = blockIdx.x;
  int b = bid >> 12;            // / SL
  int t = bid & (SL - 1);
  __shared__ float xrow[DI];
  __shared__ float gp[4][NH];
  __shared__ float gate[NH];
  int tid = threadIdx.x;
  const float* xr = xg + ((size_t)(b * SL + t)) * DI;
  ((float4*)xrow)[tid] = ((const float4*)xr)[tid];
  ((float4*)xrow)[tid + 256] = ((const float4*)xr)[tid + 256];
  __syncthreads();
  float a[NH];
#pragma unroll
  for (int h = 0; h < NH; ++h) a[h] = 0.f;
#pragma unroll
  for (int q = 0; q < 8; ++q) {
    int d = q * 256 + tid;
    float xv = xrow[d];
#pragma unroll
    for (int h = 0; h < NH; ++h) a[h] += xv * Wg[h * DI + d];
  }
#pragma unroll
  for (int h = 0; h < NH; ++h) {
    float v = a[h];
    v += __shfl_down(v, 32);
    v += __shfl_down(v, 16);
    v += __shfl_down(v, 8);
    v += __shfl_down(v, 4);
    v += __shfl_down(v, 2);
    v += __shfl_down(v, 1);
    if ((tid & 63) == 0) gp[tid >> 6][h] = v;
  }
  __syncthreads();
  if (tid < NH) gate[tid] = gp[0][tid] + gp[1][tid] + gp[2][tid] + gp[3][tid] + Dg[tid];
  __syncthreads();
  int d0 = tid * 8;
  float g = gate[tid >> 4];
  float4 f0 = make_float4(0.f, 0.f, 0.f, 0.f), f1 = f0, g0 = f0, g1 = f0;
  if (t > 0) {
    const float* yf = ytmp + ((size_t)(b * SL + (t - 1))) * DI + d0;
    f0 = ((const float4*)yf)[0]; f1 = ((const float4*)yf)[1];
  }
  if (t < SL - 1) {
    const float* yb = ytmp + ((size_t)((2 + b) * SL + (SL - 2 - t))) * DI + d0;
    g0 = ((const float4*)yb)[0]; g1 = ((const float4*)yb)[1];
  }
  float4 x0 = ((float4*)xrow)[tid * 2];
  float4 x1 = ((float4*)xrow)[tid * 2 + 1];
  float4 o0, o1;
  o0.x = f0.x + g0.x + x0.x * g; o0.y = f0.y + g0.y + x0.y * g;
  o0.z = f0.z + g0.z + x0.z * g; o0.w = f0.w + g0.w + x0.w * g;
  o1.x = f1.x + g1.x + x1.x * g; o1.y = f1.y + g1.y + x1.y * g;
  o1.z = f1.z + g1.z + x1.z * g; o1.w = f1.w + g1.w + x1.w * g;
  float* op = out + ((size_t)(b * SL + t)) * DI + d0;
  ((float4*)op)[0] = o0;
  ((float4*)op)[1] = o1;
}

extern "C" void kernel_launch(void* const* d_in, const int* in_sizes, int n_in,
                              void* d_out, int out_size, void* d_ws, size_t ws_size,
                              hipStream_t stream) {
  (void)in_sizes; (void)n_in; (void)out_size; (void)ws_size;
  const float* x     = (const float*)d_in[0];
  const float* BC    = (const float*)d_in[1];
  const float* dt    = (const float*)d_in[2];
  const float* A_log = (const float*)d_in[3];
  const float* Dg    = (const float*)d_in[4];
  const float* W     = (const float*)d_in[5];
  float* out = (float*)d_out;

  char* p = (char*)d_ws;
  float* cs  = (float*)p;                     p += (size_t)NSQ * NCH * NH * CK * 4;   // 1 MB
  float* dtv = (float*)p;                     p += (size_t)NSQ * NCH * NH * CK * 4;   // 1 MB
  float* cdec = (float*)p;                    p += (size_t)NSQ * NCH * NH * 4;        // 4 KB
  float* CBbuf = (float*)p;                   p += (size_t)NSQ * NCH * CK * CK * 4;   // 16.8 MB
  unsigned short* prevbuf = (unsigned short*)p; p += (size_t)NSQ * NCH * NH * DS * HD * 2; // 67 MB
  float* ytmp = (float*)p;                    p += (size_t)NSQ * SL * DI * 4;         // 134 MB

  hipLaunchKernelGGL(kprep,   dim3(NSQ * NCH),          dim3(CK),  0, stream, dt, A_log, cs, dtv, cdec);
  hipLaunchKernelGGL(kcb,     dim3(NSQ * NCH * 16),     dim3(256), 0, stream, BC, CBbuf);
  hipLaunchKernelGGL(kstates, dim3(NSQ * NCH * NH * 2), dim3(256), 0, stream, x, BC, cs, dtv, prevbuf);
  hipLaunchKernelGGL(kscan,   dim3(NSQ * NH * DS * HD / 256), dim3(256), 0, stream, prevbuf, cdec);
  hipLaunchKernelGGL(ky,      dim3(NSQ * NCH * NH * 2), dim3(256), 0, stream, x, BC, cs, dtv, CBbuf, prevbuf, ytmp);
  hipLaunchKernelGGL(kfinal,  dim3(NB * SL),            dim3(256), 0, stream, x, W, Dg, ytmp, out);
}

// Round 2
// 415.069 us; speedup vs baseline: 2.8635x; 2.8635x over previous
//
#include <hip/hip_runtime.h>
#include <stdint.h>

#define NB 2
#define SL 4096
#define NH 16
#define HD 128
#define DS 256
#define CK 256
#define NCH 16
#define NSQ 4
#define DI 2048

typedef unsigned short u16;
typedef unsigned int u32;
typedef __attribute__((ext_vector_type(8))) __bf16 bf16x8;
typedef __attribute__((ext_vector_type(4))) float f32x4;

__device__ __forceinline__ int tor(int dir, int t) { return dir ? (SL - 1 - t) : t; }

__device__ __forceinline__ u16 f2bf(float f) {
  u32 u = __float_as_uint(f);
  u = u + 0x7fffu + ((u >> 16) & 1u);   // RNE
  return (u16)(u >> 16);
}
__device__ __forceinline__ float bf2f(u16 s) {
  return __uint_as_float(((u32)s) << 16);
}

__device__ __forceinline__ void gl_lds16(const u16* g, u16* l) {
  __builtin_amdgcn_global_load_lds((const __attribute__((address_space(1))) u32*)g,
                                   (__attribute__((address_space(3))) u32*)l, 16, 0, 0);
}

// Stage a 128x32 bf16 tile (row stride 256 elems in global) into LDS [128][32],
// 16B chunks XOR-swizzled by ((row>>1)&3) to kill ds_read_b128 bank conflicts.
// Each wave stages rows [w*32, w*32+32).
__device__ __forceinline__ void stage_tile(const u16* __restrict__ src, u16* lds,
                                           int lane, int w, int k0) {
  int sgrow = lane >> 2, sc = lane & 3;
  int r0 = w << 5;
  int ra = r0 + sgrow, rb = ra + 16;
  int kqa = (sc ^ ((ra >> 1) & 3)) << 3;
  int kqb = (sc ^ ((rb >> 1) & 3)) << 3;
  gl_lds16(src + (size_t)ra * 256 + k0 + kqa, lds + r0 * 32);
  gl_lds16(src + (size_t)rb * 256 + k0 + kqb, lds + (r0 + 16) * 32);
}

__device__ __forceinline__ bf16x8 frag(const u16* lds, int base_row, int m, int quad) {
  int row = base_row + m;
  return *(const bf16x8*)&lds[row * 32 + ((quad ^ ((row >> 1) & 3)) << 3)];
}

__device__ __forceinline__ void mfma16(const u16* As, const u16* Bs, int wi, int wp,
                                       int m, int quad, f32x4 acc[4][4]) {
  bf16x8 af[4], bv[4];
#pragma unroll
  for (int r = 0; r < 4; ++r) af[r] = frag(As, wi + (r << 4), m, quad);
#pragma unroll
  for (int c = 0; c < 4; ++c) bv[c] = frag(Bs, wp + (c << 4), m, quad);
#pragma unroll
  for (int r = 0; r < 4; ++r)
#pragma unroll
    for (int c = 0; c < 4; ++c)
      acc[r][c] = __builtin_amdgcn_mfma_f32_16x16x32_bf16(af[r], bv[c], acc[r][c], 0, 0, 0);
}

// ---- prep: softplus(dt), per-chunk cumsum of dA -----------------------------
__global__ __launch_bounds__(256) void kprep(const float* __restrict__ dt,
                                             const float* __restrict__ A_log,
                                             float* __restrict__ csb,
                                             float* __restrict__ dtvb,
                                             float* __restrict__ cdecb) {
  int blk = blockIdx.x;                 // sj*16 + h
  int h = blk & 15, sj = blk >> 4;
  int s = sj >> 4, j = sj & 15;
  int b = s & 1, dir = s >> 1;
  int i = threadIdx.x;
  int to = tor(dir, j * CK + i);
  __shared__ float sbuf[CK];
  float a = -expf(A_log[h]);
  float raw = dt[((size_t)(b * SL + to)) * (2 * NH) + dir * NH + h];
  float sp = (raw > 20.f) ? raw : log1pf(expf(raw));
  sbuf[i] = sp * a;
  __syncthreads();
  for (int off = 1; off < CK; off <<= 1) {
    float v = (i >= off) ? sbuf[i - off] : 0.f;
    __syncthreads();
    sbuf[i] += v;
    __syncthreads();
  }
  float csv = sbuf[i];
  size_t base = ((size_t)sj * NH + h) * CK;
  csb[base + i] = csv;
  dtvb[base + i] = sp;
  if (i == CK - 1) cdecb[sj * NH + h] = expf(csv);
}

// ---- cast BC -> bf16 B/C with flip applied: [s][t][n] ------------------------
__global__ __launch_bounds__(256) void kcast(const float* __restrict__ BC,
                                             u16* __restrict__ Bbf,
                                             u16* __restrict__ Cbf) {
  int blk = blockIdx.x;                 // s*SL + t
  int s = blk >> 12, t = blk & (SL - 1);
  int b = s & 1, dir = s >> 1;
  int tsrc = tor(dir, t);
  int tid = threadIdx.x;
  const float* src = BC + ((size_t)(b * SL + tsrc)) * (2 * DS);
  size_t dstb = ((size_t)s * SL + t) * DS;
  Bbf[dstb + tid] = f2bf(src[tid]);
  Cbf[dstb + tid] = f2bf(src[DS + tid]);
}

// ---- transpose B within chunk: BbfT[sj][n][k] --------------------------------
__global__ __launch_bounds__(256) void ktransB(const u16* __restrict__ Bbf,
                                               u16* __restrict__ BbfT) {
  int sj = blockIdx.x;
  int s = sj >> 4, j = sj & 15;
  __shared__ u16 T[64 * 264];
  int tid = threadIdx.x;
  const u16* src = Bbf + ((size_t)s * SL + j * CK) * DS;
  u16* dst = BbfT + (size_t)sj * DS * CK;
  int kr = tid >> 2, part = (tid & 3) * 64;
  for (int k0 = 0; k0 < CK; k0 += 64) {
    __syncthreads();
    {
      const uint4* gs = (const uint4*)(src + (size_t)(k0 + kr) * DS + part);
      uint4* tb = (uint4*)&T[kr * 264 + part];
#pragma unroll
      for (int q = 0; q < 8; ++q) tb[q] = gs[q];
    }
    __syncthreads();
    int n = tid;
    u16 col[64];
#pragma unroll
    for (int kq = 0; kq < 64; ++kq) col[kq] = T[kq * 264 + n];
    uint4* ds_ = (uint4*)(dst + (size_t)n * CK + k0);
#pragma unroll
    for (int q = 0; q < 8; ++q) {
      uint4 wv;
      wv.x = (u32)col[q * 8 + 0] | ((u32)col[q * 8 + 1] << 16);
      wv.y = (u32)col[q * 8 + 2] | ((u32)col[q * 8 + 3] << 16);
      wv.z = (u32)col[q * 8 + 4] | ((u32)col[q * 8 + 5] << 16);
      wv.w = (u32)col[q * 8 + 6] | ((u32)col[q * 8 + 7] << 16);
      ds_[q] = wv;
    }
  }
}

// ---- xsT[inst][p][k] = bf16( x[t(k)][h*128+p] * e^{-cs_k} * dt_k ) ----------
__global__ __launch_bounds__(256) void kxsT(const float* __restrict__ xg,
                                            const float* __restrict__ csb,
                                            const float* __restrict__ dtvb,
                                            u16* __restrict__ xsT) {
  int inst = blockIdx.x;                // ((s*16+j)*16+h)
  int h = inst & 15, sj = inst >> 4;
  int s = sj >> 4, j = sj & 15;
  int b = s & 1, dir = s >> 1;
  int tid = threadIdx.x;
  __shared__ u16 Ls[128 * 40];          // [p][kk], stride 40
  size_t cbase = ((size_t)sj * NH + h) * CK;
  u16* dst = xsT + (size_t)inst * (128 * 256);
  int kk = tid >> 3;
  int pg = (tid & 7) * 16;
  int p2 = tid >> 1, half = tid & 1;
  for (int k0 = 0; k0 < CK; k0 += 32) {
    int kglob = k0 + kk;
    float sc_ = expf(-csb[cbase + kglob]) * dtvb[cbase + kglob];
    int t = tor(dir, j * CK + kglob);
    const float* src = xg + ((size_t)(b * SL + t)) * DI + h * HD + pg;
    float4 v0 = ((const float4*)src)[0];
    float4 v1 = ((const float4*)src)[1];
    float4 v2 = ((const float4*)src)[2];
    float4 v3 = ((const float4*)src)[3];
    float vv[16] = {v0.x, v0.y, v0.z, v0.w, v1.x, v1.y, v1.z, v1.w,
                    v2.x, v2.y, v2.z, v2.w, v3.x, v3.y, v3.z, v3.w};
    __syncthreads();
#pragma unroll
    for (int q = 0; q < 16; ++q) Ls[(pg + q) * 40 + kk] = f2bf(vv[q] * sc_);
    __syncthreads();
    uint4 w0 = *(const uint4*)&Ls[p2 * 40 + half * 16];
    uint4 w1 = *(const uint4*)&Ls[p2 * 40 + half * 16 + 8];
    *(uint4*)&dst[(size_t)p2 * 256 + k0 + half * 16] = w0;
    *(uint4*)&dst[(size_t)p2 * 256 + k0 + half * 16 + 8] = w1;
  }
}

// ---- CBm[sj][i][k] = bf16( sum_n C[i,n]*B[k,n] ), masked k<=i ---------------
__global__ __launch_bounds__(256) void kcb(const u16* __restrict__ Cbf,
                                           const u16* __restrict__ Bbf,
                                           u16* __restrict__ CBm) {
  int blk = blockIdx.x;
  int tri = blk % 3;                    // 0:(0,0) 1:(1,0) 2:(1,1)
  int sj = blk / 3;
  int it0 = tri ? 128 : 0;
  int kt0 = (tri == 2) ? 128 : 0;
  int s = sj >> 4, j = sj & 15;
  __shared__ u16 As[128 * 32];
  __shared__ u16 Bs[128 * 32];
  int tid = threadIdx.x;
  int w = tid >> 6, lane = tid & 63;
  int wi = (w >> 1) << 6, wp = (w & 1) << 6;
  int m = lane & 15, quad = lane >> 4;
  const u16* Ab = Cbf + ((size_t)s * SL + j * CK + it0) * DS;
  const u16* Bb = Bbf + ((size_t)s * SL + j * CK + kt0) * DS;
  f32x4 zini = {0.f, 0.f, 0.f, 0.f};
  f32x4 acc[4][4];
#pragma unroll
  for (int r = 0; r < 4; ++r)
#pragma unroll
    for (int c = 0; c < 4; ++c) acc[r][c] = zini;
  for (int ks = 0; ks < 8; ++ks) {
    int k0 = ks << 5;
    stage_tile(Ab, As, lane, w, k0);
    stage_tile(Bb, Bs, lane, w, k0);
    __syncthreads();
    mfma16(As, Bs, wi, wp, m, quad, acc);
    __syncthreads();
  }
  int diag = (it0 == kt0);
  u16* dst = CBm + ((size_t)sj * CK + it0) * CK + kt0;
#pragma unroll
  for (int r = 0; r < 4; ++r)
#pragma unroll
    for (int rg = 0; rg < 4; ++rg) {
      int irow = wi + (r << 4) + (quad << 2) + rg;
#pragma unroll
      for (int c = 0; c < 4; ++c) {
        int kcol = wp + (c << 4) + m;
        float v = acc[r][c][rg];
        if (diag && kcol > irow) v = 0.f;
        dst[(size_t)irow * CK + kcol] = f2bf(v);
      }
    }
}

// ---- states: prevT[inst][p][n] = e^{cs_last} * sum_k xs[p,k]*B[n,k] ----------
__global__ __launch_bounds__(256) void kstates(const u16* __restrict__ xsT,
                                               const u16* __restrict__ BbfT,
                                               const float* __restrict__ cdecb,
                                               u16* __restrict__ prevT) {
  int blk = blockIdx.x;
  int ntile = blk & 1;
  int inst = blk >> 1;
  int h = inst & 15, sj = inst >> 4;
  int nt0 = ntile << 7;
  __shared__ u16 As[128 * 32];
  __shared__ u16 Bs[128 * 32];
  int tid = threadIdx.x;
  int w = tid >> 6, lane = tid & 63;
  int wi = (w >> 1) << 6, wp = (w & 1) << 6;
  int m = lane & 15, quad = lane >> 4;
  const u16* Ab = xsT + (size_t)inst * (128 * 256);        // rows p
  const u16* Bb = BbfT + ((size_t)sj * DS + nt0) * CK;     // rows n
  f32x4 zini = {0.f, 0.f, 0.f, 0.f};
  f32x4 acc[4][4];
#pragma unroll
  for (int r = 0; r < 4; ++r)
#pragma unroll
    for (int c = 0; c < 4; ++c) acc[r][c] = zini;
  for (int ks = 0; ks < 8; ++ks) {
    int k0 = ks << 5;
    stage_tile(Ab, As, lane, w, k0);
    stage_tile(Bb, Bs, lane, w, k0);
    __syncthreads();
    mfma16(As, Bs, wi, wp, m, quad, acc);
    __syncthreads();
  }
  float scale = cdecb[sj * NH + h];
  u16* dst = prevT + (size_t)inst * (128 * 256) + nt0;
#pragma unroll
  for (int r = 0; r < 4; ++r)
#pragma unroll
    for (int rg = 0; rg < 4; ++rg) {
      int prow = wi + (r << 4) + (quad << 2) + rg;
#pragma unroll
      for (int c = 0; c < 4; ++c) {
        int ncol = wp + (c << 4) + m;
        dst[(size_t)prow * 256 + ncol] = f2bf(acc[r][c][rg] * scale);
      }
    }
}

// ---- inter-chunk recurrence over prevT[s][j][h][p][n] ------------------------
__global__ __launch_bounds__(256) void kscan(u16* __restrict__ prevT,
                                             const float* __restrict__ cdecb) {
  int g = blockIdx.x * 256 + threadIdx.x;
  int n = g & 255;
  int p = (g >> 8) & 127;
  int h = (g >> 15) & 15;
  int s = g >> 19;
  size_t base = (((size_t)(s * 256 + h) * 128) + p) * 256 + n;
  const size_t stride = (size_t)NH * 128 * 256;
  float carry = 0.f;
  for (int j = 0; j < NCH; ++j) {
    size_t idx = base + (size_t)j * stride;
    float sv = bf2f(prevT[idx]);
    prevT[idx] = f2bf(carry);
    carry = carry * cdecb[(s * NCH + j) * NH + h] + sv;
  }
}

// ---- y[i,p] = e^{cs_i} * ( CBm(i,:)·xs(:,p) + C(i,:)·prev(:,p) ) -------------
__global__ __launch_bounds__(256) void ky(const u16* __restrict__ CBm,
                                          const u16* __restrict__ Cbf,
                                          const u16* __restrict__ xsT,
                                          const u16* __restrict__ prevT,
                                          const float* __restrict__ csb,
                                          u16* __restrict__ ytmpb) {
  int blk = blockIdx.x;
  int itile = blk & 1;
  int inst = blk >> 1;
  int h = inst & 15, sj = inst >> 4;
  int s = sj >> 4, j = sj & 15;
  int it0 = itile << 7;
  __shared__ u16 As[128 * 32];
  __shared__ u16 Bs[128 * 32];
  int tid = threadIdx.x;
  int w = tid >> 6, lane = tid & 63;
  int wi = (w >> 1) << 6, wp = (w & 1) << 6;
  int m = lane & 15, quad = lane >> 4;

  const u16* Ai = CBm + ((size_t)sj * CK + it0) * CK;
  const u16* Ae = Cbf + ((size_t)s * SL + j * CK + it0) * DS;
  const u16* Bi = xsT + (size_t)inst * (128 * 256);
  const u16* Be = prevT + (size_t)inst * (128 * 256);

  int nIntra = itile ? 8 : 4;           // upper-zero CB tiles skipped for itile 0
  int nTot = nIntra + 8;

  f32x4 zini = {0.f, 0.f, 0.f, 0.f};
  f32x4 acc[4][4];
#pragma unroll
  for (int r = 0; r < 4; ++r)
#pragma unroll
    for (int c = 0; c < 4; ++c) acc[r][c] = zini;

  for (int ks = 0; ks < nTot; ++ks) {
    int intra = ks < nIntra;
    int k0 = (intra ? ks : ks - nIntra) << 5;
    const u16* Ab = intra ? Ai : Ae;
    const u16* Bb = intra ? Bi : Be;
    stage_tile(Ab, As, lane, w, k0);
    stage_tile(Bb, Bs, lane, w, k0);
    __syncthreads();
    mfma16(As, Bs, wi, wp, m, quad, acc);
    __syncthreads();
  }
  const float* csrow = csb + ((size_t)sj * NH + h) * CK + it0;
  u16* yb = ytmpb + ((size_t)s * SL + j * CK + it0) * DI + h * HD;
#pragma unroll
  for (int r = 0; r < 4; ++r)
#pragma unroll
    for (int rg = 0; rg < 4; ++rg) {
      int irow = wi + (r << 4) + (quad << 2) + rg;
      float esc = expf(csrow[irow]);
#pragma unroll
      for (int c = 0; c < 4; ++c) {
        int pcol = wp + (c << 4) + m;
        yb[(size_t)irow * DI + pcol] = f2bf(acc[r][c][rg] * esc);
      }
    }
}

// ---- final: out = roll(y_fw) + flip(roll(y_bw)) + x * repeat(x@W^T + D) ------
__device__ __forceinline__ void unpk8(uint4 u, float* o) {
  o[0] = __uint_as_float(u.x << 16); o[1] = __uint_as_float(u.x & 0xffff0000u);
  o[2] = __uint_as_float(u.y << 16); o[3] = __uint_as_float(u.y & 0xffff0000u);
  o[4] = __uint_as_float(u.z << 16); o[5] = __uint_as_float(u.z & 0xffff0000u);
  o[6] = __uint_as_float(u.w << 16); o[7] = __uint_as_float(u.w & 0xffff0000u);
}

__global__ __launch_bounds__(256) void kfinal(const float* __restrict__ xg,
                                              const float* __restrict__ Wg,
                                              const float* __restrict__ Dg,
                                              const u16* __restrict__ ytmpb,
                                              float* __restrict__ out) {
  int bid = blockIdx.x;
  int b = bid >> 12;
  int t = bid & (SL - 1);
  __shared__ float xrow[DI];
  __shared__ float gp[4][NH];
  __shared__ float gate[NH];
  int tid = threadIdx.x;
  const float* xr = xg + ((size_t)(b * SL + t)) * DI;
  ((float4*)xrow)[tid] = ((const float4*)xr)[tid];
  ((float4*)xrow)[tid + 256] = ((const float4*)xr)[tid + 256];
  __syncthreads();
  float a[NH];
#pragma unroll
  for (int h = 0; h < NH; ++h) a[h] = 0.f;
#pragma unroll
  for (int q = 0; q < 8; ++q) {
    int d = q * 256 + tid;
    float xv = xrow[d];
#pragma unroll
    for (int h = 0; h < NH; ++h) a[h] += xv * Wg[h * DI + d];
  }
#pragma unroll
  for (int h = 0; h < NH; ++h) {
    float v = a[h];
    v += __shfl_down(v, 32);
    v += __shfl_down(v, 16);
    v += __shfl_down(v, 8);
    v += __shfl_down(v, 4);
    v += __shfl_down(v, 2);
    v += __shfl_down(v, 1);
    if ((tid & 63) == 0) gp[tid >> 6][h] = v;
  }
  __syncthreads();
  if (tid < NH) gate[tid] = gp[0][tid] + gp[1][tid] + gp[2][tid] + gp[3][tid] + Dg[tid];
  __syncthreads();
  int d0 = tid * 8;
  float g = gate[tid >> 4];
  float fy[8] = {0.f, 0.f, 0.f, 0.f, 0.f, 0.f, 0.f, 0.f};
  float by[8] = {0.f, 0.f, 0.f, 0.f, 0.f, 0.f, 0.f, 0.f};
  if (t > 0) {
    uint4 u = *(const uint4*)(ytmpb + ((size_t)(b * SL + (t - 1))) * DI + d0);
    unpk8(u, fy);
  }
  if (t < SL - 1) {
    uint4 u = *(const uint4*)(ytmpb + ((size_t)((2 + b) * SL + (SL - 2 - t))) * DI + d0);
    unpk8(u, by);
  }
  float* op = out + ((size_t)(b * SL + t)) * DI + d0;
#pragma unroll
  for (int q = 0; q < 8; ++q)
    op[q] = fy[q] + by[q] + xrow[d0 + q] * g;
}

extern "C" void kernel_launch(void* const* d_in, const int* in_sizes, int n_in,
                              void* d_out, int out_size, void* d_ws, size_t ws_size,
                              hipStream_t stream) {
  (void)in_sizes; (void)n_in; (void)out_size; (void)ws_size;
  const float* x     = (const float*)d_in[0];
  const float* BC    = (const float*)d_in[1];
  const float* dt    = (const float*)d_in[2];
  const float* A_log = (const float*)d_in[3];
  const float* Dg    = (const float*)d_in[4];
  const float* W     = (const float*)d_in[5];
  float* out = (float*)d_out;

  char* p = (char*)d_ws;
  float* cs   = (float*)p;  p += (size_t)NSQ * NCH * NH * CK * 4;        // 1 MB
  float* dtv  = (float*)p;  p += (size_t)NSQ * NCH * NH * CK * 4;        // 1 MB
  float* cdec = (float*)p;  p += (size_t)NSQ * NCH * NH * 4;             // 4 KB
  u16* Bbf    = (u16*)p;    p += (size_t)NSQ * SL * DS * 2;              // 8.4 MB
  u16* Cbf    = (u16*)p;    p += (size_t)NSQ * SL * DS * 2;              // 8.4 MB
  u16* BbfT   = (u16*)p;    p += (size_t)NSQ * NCH * DS * CK * 2;        // 8.4 MB
  u16* CBm    = (u16*)p;    p += (size_t)NSQ * NCH * CK * CK * 2;        // 8.4 MB
  u16* xsT    = (u16*)p;    p += (size_t)NSQ * NCH * NH * HD * CK * 2;   // 67 MB
  u16* prevT  = (u16*)p;    p += (size_t)NSQ * NCH * NH * HD * DS * 2;   // 67 MB
  u16* ytmpb  = (u16*)p;    p += (size_t)NSQ * SL * DI * 2;              // 67 MB

  hipLaunchKernelGGL(kprep,   dim3(NSQ * NCH * NH),      dim3(CK),  0, stream, dt, A_log, cs, dtv, cdec);
  hipLaunchKernelGGL(kcast,   dim3(NSQ * SL),            dim3(256), 0, stream, BC, Bbf, Cbf);
  hipLaunchKernelGGL(ktransB, dim3(NSQ * NCH),           dim3(256), 0, stream, Bbf, BbfT);
  hipLaunchKernelGGL(kxsT,    dim3(NSQ * NCH * NH),      dim3(256), 0, stream, x, cs, dtv, xsT);
  hipLaunchKernelGGL(kcb,     dim3(NSQ * NCH * 3),       dim3(256), 0, stream, Cbf, Bbf, CBm);
  hipLaunchKernelGGL(kstates, dim3(NSQ * NCH * NH * 2),  dim3(256), 0, stream, xsT, BbfT, cdec, prevT);
  hipLaunchKernelGGL(kscan,   dim3(NSQ * NH * HD * DS / 256), dim3(256), 0, stream, prevT, cdec);
  hipLaunchKernelGGL(ky,      dim3(NSQ * NCH * NH * 2),  dim3(256), 0, stream, CBm, Cbf, xsT, prevT, cs, ytmpb);
  hipLaunchKernelGGL(kfinal,  dim3(NB * SL),             dim3(256), 0, stream, x, W, Dg, ytmpb, out);
}